// Round 7
// baseline (5623.104 us; speedup 1.0000x reference)
//
#include <hip/hip_runtime.h>
#include <cstddef>

// SimpleLSTM: B=64, D=512, T=512, H=1024, O=1 — fp16, TAGGED-H push sync
// (flag IS the data: h words are (tag<<16)|f16; one store + one poll per edge)
// ws layout (~44.5 MiB):
//   [0, 32MB)            xT: f16 [T=512][B=64][D=512]
//   [32MB, +12.58MB)     Wf: f16 A-frags [r=64][ks=48][mt=4][lane=64][8]
//                        (reused after weight load as out-partials
//                         part[t=512][g=4][r=64][b16=16] f32 = 8MB, atomicAdd'd)
//   [46,137,344, +512KB) hT: u32 tagged h [2 parity][B=64][H=1024]
//   [46,661,632, +4B)    ready counter
#define WS_XT_OFF   0ull
#define WS_WF_OFF   33554432ull
#define WS_HB_OFF   46137344ull
#define WS_CTR_OFF  46661632ull

typedef _Float16 f16x8 __attribute__((ext_vector_type(8)));
typedef float    f32x4 __attribute__((ext_vector_type(4)));
typedef unsigned short u16;
typedef unsigned int   u32;
typedef unsigned long long u64;

__device__ __forceinline__ u16 f2h(float f) {
  _Float16 h = (_Float16)f;                     // v_cvt_f16_f32, RNE
  return __builtin_bit_cast(u16, h);
}
__device__ __forceinline__ float sigm(float x) { return 1.0f / (1.0f + __expf(-x)); }

// ---------- K0: init hT parity0 = 0 (h0=0, tag 0), ready = 0 ----------
__global__ __launch_bounds__(256) void k_init(u32* hT, u32* ready) {
  int t = blockIdx.x * 256 + threadIdx.x;       // 32768 threads
  ((u64*)hT)[t] = 0ull;                         // 262144 B = parity-0 buffer
  if (t == 0) ready[0] = 0u;
}

// ---------- K1: x (B,D,T) f32 -> xT[t][b][d] f16 ----------
__global__ __launch_bounds__(256) void k_xpose(const float* __restrict__ x,
                                               u16* __restrict__ xT) {
  __shared__ float lds[64][65];
  const int d0 = blockIdx.x * 64, t0 = blockIdx.y * 64, b = blockIdx.z;
  const int tid = threadIdx.x;
  const int tt = tid & 63, dr = tid >> 6;
  const float* xp = x + ((size_t)b * 512 + d0) * 512 + t0 + tt;
#pragma unroll
  for (int i = 0; i < 16; ++i) {
    int dd = i * 4 + dr;
    lds[dd][tt] = xp[(size_t)dd * 512];
  }
  __syncthreads();
  const int dp = tid & 31, rr = tid >> 5;
#pragma unroll
  for (int i = 0; i < 8; ++i) {
    int tt2 = i * 8 + rr;
    u32 lo = f2h(lds[dp * 2][tt2]);
    u32 hi = f2h(lds[dp * 2 + 1][tt2]);
    *(u32*)(xT + ((size_t)(t0 + tt2) * 64 + b) * 512 + d0 + dp * 2) = lo | (hi << 16);
  }
}

// ---------- K2: pack [W_ih | W_hh] rows into per-lane MFMA A-fragments (f16) ----------
// chunk c = (r*48 + ks)*4 + mt ; within-tile row m: gate=m&3, j=r*16+mt*4+(m>>2)
__global__ __launch_bounds__(256) void k_wfrag(const float* __restrict__ W_ih,
                                               const float* __restrict__ W_hh,
                                               u16* __restrict__ Wf) {
  int g = blockIdx.x * 256 + threadIdx.x;       // 786432 threads
  int lane = g & 63;
  int c  = g >> 6;                              // [0, 12288)
  int mt = c & 3;
  int cc = c >> 2;
  int ks = cc % 48;
  int r  = cc / 48;
  int m = lane & 15, q = lane >> 4;
  int gate = m & 3;
  int j = r * 16 + mt * 4 + (m >> 2);
  int row = gate * 1024 + j;
  const float* src = (ks < 16) ? (W_ih + (size_t)row * 512 + ks * 32 + q * 8)
                               : (W_hh + (size_t)row * 1024 + (ks - 16) * 32 + q * 8);
  union { u16 s[8]; uint4 v; } U;
#pragma unroll
  for (int i = 0; i < 8; ++i) U.s[i] = f2h(src[i]);
  *(uint4*)(Wf + ((size_t)c * 64 + lane) * 8) = U.v;
}

// ---------- K3: persistent cooperative recurrence ----------
// grid 256 = 4 groups x 64 blocks; block 512 = 8 waves; 1 block/CU.
// Wave w: k-steps {2w, 2w+1} (x) and {16+4w..16+4w+3} (h rows [128w,128w+128),
// produced by blocks [8w,8w+8)). Union over w covers all 64 producers before
// each block's barrier => parity reuse at t+2 is safe (2-step lag guard).
// h exchange: tagged u32 words (tag==t valid at iteration t), LLC-direct.
__global__ __launch_bounds__(512, 2) void k_lstm(
    const u16* __restrict__ xT, const u16* __restrict__ Wf,
    u32* hT, u32* ready,
    const float* __restrict__ b_ih, const float* __restrict__ b_hh,
    const float* __restrict__ W_out, float* __restrict__ part) {
  __shared__ f32x4 red[2][8 * 4 * 64];    // [parity][wave][mt][lane], 64 KB
  const int tid = threadIdx.x;
  const int w = tid >> 6, lane = tid & 63;
  const int blk = blockIdx.x, g = blk >> 6, r = blk & 63;
  const int bg0 = g * 16, j0 = r * 16;
  const int n = lane & 15, q = lane >> 4;

  // Step-invariant weights -> registers
  f16x8 wfr[6][4];
#pragma unroll
  for (int kl = 0; kl < 6; ++kl) {
    int ks = (kl < 2) ? (2 * w + kl) : (16 + 4 * w + (kl - 2));
#pragma unroll
    for (int mt = 0; mt < 4; ++mt) {
      size_t c = ((size_t)r * 48 + ks) * 4 + mt;
      wfr[kl][mt] = *(const f16x8*)(Wf + (c * 64 + lane) * 8);
    }
  }

  float bias0 = 0.f, bias1 = 0.f, bias2 = 0.f, bias3 = 0.f, wout = 0.f;
  if (w < 4) {
    int j = j0 + w * 4 + q;
    bias0 = b_ih[j]        + b_hh[j];
    bias1 = b_ih[1024 + j] + b_hh[1024 + j];
    bias2 = b_ih[2048 + j] + b_hh[2048 + j];
    bias3 = b_ih[3072 + j] + b_hh[3072 + j];
    wout  = W_out[j];
  }

  // One-time grid barrier: all Wf loads done before part[] overwrites Wf
  __syncthreads();                        // each wave drains vmcnt -> wfr in regs
  if (tid == 0) {
    __hip_atomic_fetch_add(ready, 1u, __ATOMIC_RELAXED, __HIP_MEMORY_SCOPE_AGENT);
    while (__hip_atomic_load(ready, __ATOMIC_RELAXED, __HIP_MEMORY_SCOPE_AGENT) < 256u)
      __builtin_amdgcn_s_sleep(8);
  }
  __syncthreads();
  // zero own out-partial slice part[t=tid][g][r][0..16)
  {
    f32x4 z = {0.f, 0.f, 0.f, 0.f};
    f32x4* p4 = (f32x4*)&part[((size_t)(tid * 4 + g) * 64 + r) * 16];
    p4[0] = z; p4[1] = z; p4[2] = z; p4[3] = z;
  }
  __syncthreads();                        // drain zero stores before any atomicAdd
  asm volatile("" ::: "memory");

  u32* hT0 = hT;                          // parity 0: [b][j] tagged u32
  u32* hT1 = hT + 65536;
  float c_state = 0.f;
  const f32x4 zero = {0.f, 0.f, 0.f, 0.f};

  for (int t = 0; t < 512; ++t) {
    const u32* hcur = (t & 1) ? hT1 : hT0;    // holds h_t (tag t)
    u32* hnxt       = (t & 1) ? hT0 : hT1;    // receives h_{t+1} (tag t+1)
    const u16* xtb  = xT + (size_t)t * 32768;

    // poll addresses for this wave's 4 h fragments (8 x dwordx4)
    const u32* hb = hcur + (bg0 + n) * 1024;
    const u32* p0 = hb + (4 * w + 0) * 32 + q * 8;
    const u32* p1 = p0 + 4;
    const u32* p2 = hb + (4 * w + 1) * 32 + q * 8;
    const u32* p3 = p2 + 4;
    const u32* p4 = hb + (4 * w + 2) * 32 + q * 8;
    const u32* p5 = p4 + 4;
    const u32* p6 = hb + (4 * w + 3) * 32 + q * 8;
    const u32* p7 = p6 + 4;

    // flag-independent x loads (ks = 2w, 2w+1)
    f16x8 bfr[6];
#pragma unroll
    for (int kl = 0; kl < 2; ++kl)
      bfr[kl] = *(const f16x8*)(xtb + (bg0 + n) * 512 + (2 * w + kl) * 32 + q * 8);

    // poll own tagged h data: data arrives WITH the tag check
    uint4 a0, a1, a2, a3, a4, a5, a6, a7;
    for (;;) {
      asm volatile("global_load_dwordx4 %0, %1, off sc0 sc1" : "=&v"(a0) : "v"(p0));
      asm volatile("global_load_dwordx4 %0, %1, off sc0 sc1" : "=&v"(a1) : "v"(p1));
      asm volatile("global_load_dwordx4 %0, %1, off sc0 sc1" : "=&v"(a2) : "v"(p2));
      asm volatile("global_load_dwordx4 %0, %1, off sc0 sc1" : "=&v"(a3) : "v"(p3));
      asm volatile("global_load_dwordx4 %0, %1, off sc0 sc1" : "=&v"(a4) : "v"(p4));
      asm volatile("global_load_dwordx4 %0, %1, off sc0 sc1" : "=&v"(a5) : "v"(p5));
      asm volatile("global_load_dwordx4 %0, %1, off sc0 sc1" : "=&v"(a6) : "v"(p6));
      asm volatile("global_load_dwordx4 %0, %1, off sc0 sc1" : "=&v"(a7) : "v"(p7));
      asm volatile("s_waitcnt vmcnt(0)" ::: "memory");
      u32 bad = 0, tt = (u32)t;
      bad |= (a0.x >> 16) ^ tt; bad |= (a0.y >> 16) ^ tt; bad |= (a0.z >> 16) ^ tt; bad |= (a0.w >> 16) ^ tt;
      bad |= (a1.x >> 16) ^ tt; bad |= (a1.y >> 16) ^ tt; bad |= (a1.z >> 16) ^ tt; bad |= (a1.w >> 16) ^ tt;
      bad |= (a2.x >> 16) ^ tt; bad |= (a2.y >> 16) ^ tt; bad |= (a2.z >> 16) ^ tt; bad |= (a2.w >> 16) ^ tt;
      bad |= (a3.x >> 16) ^ tt; bad |= (a3.y >> 16) ^ tt; bad |= (a3.z >> 16) ^ tt; bad |= (a3.w >> 16) ^ tt;
      bad |= (a4.x >> 16) ^ tt; bad |= (a4.y >> 16) ^ tt; bad |= (a4.z >> 16) ^ tt; bad |= (a4.w >> 16) ^ tt;
      bad |= (a5.x >> 16) ^ tt; bad |= (a5.y >> 16) ^ tt; bad |= (a5.z >> 16) ^ tt; bad |= (a5.w >> 16) ^ tt;
      bad |= (a6.x >> 16) ^ tt; bad |= (a6.y >> 16) ^ tt; bad |= (a6.z >> 16) ^ tt; bad |= (a6.w >> 16) ^ tt;
      bad |= (a7.x >> 16) ^ tt; bad |= (a7.y >> 16) ^ tt; bad |= (a7.z >> 16) ^ tt; bad |= (a7.w >> 16) ^ tt;
      if (__all(bad == 0)) break;
    }

    // unpack low halves -> f16x8 B-fragments (tags dropped)
#pragma unroll
    for (int kl = 0; kl < 4; ++kl) {
      uint4 lo = (kl == 0) ? a0 : (kl == 1) ? a2 : (kl == 2) ? a4 : a6;
      uint4 hi = (kl == 0) ? a1 : (kl == 1) ? a3 : (kl == 2) ? a5 : a7;
      union { u32 u[4]; f16x8 v; } U;
      U.u[0] = (lo.x & 0xffffu) | (lo.y << 16);
      U.u[1] = (lo.z & 0xffffu) | (lo.w << 16);
      U.u[2] = (hi.x & 0xffffu) | (hi.y << 16);
      U.u[3] = (hi.z & 0xffffu) | (hi.w << 16);
      bfr[2 + kl] = U.v;
    }

    f32x4 acc[4];
#pragma unroll
    for (int mt = 0; mt < 4; ++mt)
      acc[mt] = __builtin_amdgcn_mfma_f32_16x16x32_f16(wfr[0][mt], bfr[0], zero, 0, 0, 0);
#pragma unroll
    for (int kl = 1; kl < 6; ++kl)
#pragma unroll
      for (int mt = 0; mt < 4; ++mt)
        acc[mt] = __builtin_amdgcn_mfma_f32_16x16x32_f16(wfr[kl][mt], bfr[kl], acc[mt], 0, 0, 0);

#pragma unroll
    for (int mt = 0; mt < 4; ++mt)
      red[t & 1][(w * 4 + mt) * 64 + lane] = acc[mt];
    __syncthreads();                      // the ONLY barrier per step

    if (w < 4) {
      const int mt = w;
      f32x4 s = zero;
#pragma unroll
      for (int wv = 0; wv < 8; ++wv)
        s += red[t & 1][(wv * 4 + mt) * 64 + lane];
      // lane owns all 4 gates of (b = bg0+n, j = j0+mt*4+q): regs = i,f,g,o
      float gi = s.x + bias0, gf = s.y + bias1, gg = s.z + bias2, go = s.w + bias3;
      c_state = sigm(gf) * c_state + sigm(gi) * tanhf(gg);
      float h = sigm(go) * tanhf(c_state);
      // tagged store: fire-and-forget, no drain, no flag
      u32 word = ((u32)(t + 1) << 16) | (u32)__builtin_bit_cast(u16, (_Float16)h);
      u32* dst = hnxt + (bg0 + n) * 1024 + j0 + mt * 4 + q;
      asm volatile("global_store_dword %0, %1, off sc0 sc1" :: "v"(dst), "v"(word) : "memory");
      // fused out-projection partial (fire-and-forget, own-L2 atomic)
      float p = h * wout;
      p += __shfl_xor(p, 16);
      p += __shfl_xor(p, 32);
      if (lane < 16)
        __hip_atomic_fetch_add(&part[((size_t)(t * 4 + g) * 64 + r) * 16 + lane], p,
                               __ATOMIC_RELAXED, __HIP_MEMORY_SCOPE_WORKGROUP);
    }
  }
}

// ---------- K4: out[b][t] = b_out + sum_r part[t][g][r][b&15] ----------
__global__ __launch_bounds__(256) void k_out(const float* __restrict__ part,
                                             const float* __restrict__ b_out,
                                             float* __restrict__ out) {
  int gi = blockIdx.x * 256 + threadIdx.x;      // 32768 threads
  int t = gi >> 6, b = gi & 63, g = b >> 4, b16 = b & 15;
  const float* p = part + ((size_t)(t * 4 + g) * 64) * 16 + b16;
  float s = b_out[0];
#pragma unroll 8
  for (int r = 0; r < 64; ++r) s += p[r * 16];
  out[(size_t)b * 512 + t] = s;
}

extern "C" void kernel_launch(void* const* d_in, const int* in_sizes, int n_in,
                              void* d_out, int out_size, void* d_ws, size_t ws_size,
                              hipStream_t stream) {
  const float* x    = (const float*)d_in[0];
  const float* W_ih = (const float*)d_in[1];
  const float* W_hh = (const float*)d_in[2];
  const float* b_ih = (const float*)d_in[3];
  const float* b_hh = (const float*)d_in[4];
  const float* Wout = (const float*)d_in[5];
  const float* bout = (const float*)d_in[6];
  float* out = (float*)d_out;

  unsigned char* ws = (unsigned char*)d_ws;
  u16* xT   = (u16*)(ws + WS_XT_OFF);
  u16* Wf   = (u16*)(ws + WS_WF_OFF);
  u32* hT   = (u32*)(ws + WS_HB_OFF);
  u32* rdy  = (u32*)(ws + WS_CTR_OFF);
  float* part = (float*)(ws + WS_WF_OFF);       // reuses Wf region after load

  k_init<<<128, 256, 0, stream>>>(hT, rdy);
  k_xpose<<<dim3(8, 8, 64), 256, 0, stream>>>(x, xT);
  k_wfrag<<<3072, 256, 0, stream>>>(W_ih, W_hh, Wf);

  void* args[8] = {&xT, &Wf, &hT, &rdy, &b_ih, &b_hh, &Wout, &part};
  hipLaunchCooperativeKernel((const void*)k_lstm, dim3(256), dim3(512), args, 0, stream);

  k_out<<<128, 256, 0, stream>>>(part, bout, out);
}